// Round 11
// baseline (115.671 us; speedup 1.0000x reference)
//
#include <hip/hip_runtime.h>

#define N 192
#define CCHUNK 8              // c columns per s1 block (B-frag reuse)
#define NCHUNK 28             // 224 / 8 chunks of c per db
#define XT 39                 // x-tile width per block (32 + CCHUNK - 1)
#define XP 41                 // x-tile LDS pitch (f32) - conflict spreading
#define NREP_S1 8             // s1 probe work multiplier
#define NREP_PREP 16          // prep probe work multiplier

typedef __attribute__((ext_vector_type(8))) short short8;   // 8 bf16
typedef __attribute__((ext_vector_type(4))) float f32x4;

static __device__ __forceinline__ unsigned short f2bf(float x) {
    uint32_t u = __builtin_bit_cast(uint32_t, x);
    u += 0x7FFFu + ((u >> 16) & 1u);          // RNE (inputs finite)
    return (unsigned short)(u >> 16);
}

// ---------------------------------------------------------------------------
// prep core: Abf[r][c] packed (bf16 Ar, bf16 -Ai), zero pad row/col 383;
// Wt[dx][dy] packed (bf16 Wr, bf16 Wi).
// ---------------------------------------------------------------------------
static __device__ __forceinline__ void prep_body(int idx, float z,
                                                 const float* __restrict__ fr,
                                                 const float* __restrict__ fi,
                                                 uint32_t* __restrict__ Abf,
                                                 uint32_t* __restrict__ Wt) {
    if (idx < 384 * 384) {
        int r = idx / 384, c = idx - r * 384;
        uint32_t pack = 0u;
        if (r < 383 && c < 383) {
            const float X0 = 191.00005f;      // 0.5*(2*192 + 1e-4) - 1
            float xr = (float)r - X0;
            float yc = (float)c - X0;
            float r2 = xr * xr + yc * yc;
            float R2 = r2 + z * z;
            float R  = sqrtf(R2);
            float amp = z / R2;
            float ph = 12.566371f * R;        // 2*pi/0.5
            float sv, cv;
            sincosf(ph, &sv, &cv);
            pack = (uint32_t)f2bf(amp * cv) | ((uint32_t)f2bf(-amp * sv) << 16);
        }
        Abf[idx] = pack;
    }
    if (idx < N * N) {
        int dy = idx / N, dx = idx - dy * N;
        Wt[dx * N + dy] = (uint32_t)f2bf(fr[idx]) | ((uint32_t)f2bf(fi[idx]) << 16);
    }
}

__global__ __launch_bounds__(256) void prep_kernel(const float* __restrict__ fr,
                                                   const float* __restrict__ fi,
                                                   const float* __restrict__ zp,
                                                   uint32_t* __restrict__ Abf,
                                                   uint32_t* __restrict__ Wt,
                                                   float* __restrict__ out) {
    int idx = blockIdx.x * 256 + threadIdx.x;
    prep_body(idx, zp[0], fr, fi, Abf, Wt);
    if (idx < N * N) out[idx] = 0.f;          // zero the atomic target each call
}

// PROBE: 16x prep work into scratch (identical values, benign race) + zero
// the s1-probe accumulation planes (unique gid) each call.
__global__ __launch_bounds__(256) void prep_probe(const float* __restrict__ fr,
                                                  const float* __restrict__ fi,
                                                  const float* __restrict__ zp,
                                                  uint32_t* __restrict__ Abf2,
                                                  uint32_t* __restrict__ Wt2,
                                                  float* __restrict__ Pscr) {
    int idx = (blockIdx.x % 576) * 256 + threadIdx.x;
    prep_body(idx, zp[0], fr, fi, Abf2, Wt2);
    int gid = blockIdx.x * 256 + threadIdx.x;
    if (gid < NREP_S1 * N * N) Pscr[gid] = 0.f;
}

// ---------------------------------------------------------------------------
// stage 1 body: G[c][y][dx] = sum_dy Ar[y+dy][c]*Wr[dy][dx] - Ai[..]*Wi[..]
// via mfma_f32_16x16x32_bf16 (K=384); dx-contraction folded in-block into
// LDS f32 tile outT[64][39] (x = c - dx), flushed with atomicAdd into
// flipped `out`. A columns staged as 16B quads, two per buffer.
// ---------------------------------------------------------------------------
static __device__ __forceinline__ void s1_body(const uint32_t* __restrict__ Abf,
                                               const uint32_t* __restrict__ Wt,
                                               float* __restrict__ out,
                                               int yoff) {
    __shared__ uint4 colAq[2][2][384];        // [buf][col-of-pair][slot] 24.6 KB
    __shared__ float outT[64 * XP];           // 10.5 KB per-block output tile

    const int tid  = threadIdx.x;
    const int l    = tid & 63;
    const int w    = tid >> 6;                // wave -> y-tile within third
    const int db   = blockIdx.x / NCHUNK;
    const int ck   = blockIdx.x - db * NCHUNK;
    const int ci0  = ck * CCHUNK;
    const int dx0  = db * 32;
    const int m    = l & 15;
    const int kg   = l >> 4;

    // B fragments: loaded once, live in registers for all 8 c's.
    uint4 bfr[2][12];
    #pragma unroll
    for (int t = 0; t < 2; ++t) {
        int dx = dx0 + t * 16 + m;
        #pragma unroll
        for (int ks = 0; ks < 12; ++ks)
            bfr[t][ks] = *(const uint4*)(Wt + dx * N + ks * 16 + kg * 4);
    }

    // zero the output tile
    for (int e = tid; e < 64 * XP; e += 256) outT[e] = 0.f;

    // stage first column pair (rows c0, c0+1 of Abf; A symmetric)
    {
        const uint32_t* a0 = Abf + (dx0 + ci0) * 384;
        const uint32_t* a1 = Abf + (dx0 + ci0 + 1) * 384;
        for (int i = tid; i < 384; i += 256) {
            uint4 v0, v1;
            __builtin_memcpy(&v0, a0 + i, 16);
            __builtin_memcpy(&v1, a1 + i, 16);
            colAq[0][0][i] = v0;
            colAq[0][1][i] = v1;
        }
    }
    __syncthreads();

    for (int p = 0; p < CCHUNK; p += 2) {
        const int cur = (p >> 1) & 1;
        if (p < CCHUNK - 2) {
            const uint32_t* a0 = Abf + (dx0 + ci0 + p + 2) * 384;
            const uint32_t* a1 = Abf + (dx0 + ci0 + p + 3) * 384;
            for (int i = tid; i < 384; i += 256) {
                uint4 v0, v1;
                __builtin_memcpy(&v0, a0 + i, 16);
                __builtin_memcpy(&v1, a1 + i, 16);
                colAq[cur ^ 1][0][i] = v0;
                colAq[cur ^ 1][1][i] = v1;
            }
        }

        #pragma unroll
        for (int h = 0; h < 2; ++h) {
            const int q  = p + h;
            const int ci = ci0 + q;
            f32x4 acc0 = {0.f, 0.f, 0.f, 0.f};
            f32x4 acc1 = {0.f, 0.f, 0.f, 0.f};
            const int srow = yoff + w * 16 + m;
            #pragma unroll
            for (int ks = 0; ks < 12; ++ks) {
                int s = srow + ks * 16 + kg * 4;      // <= 379
                uint4 aq = colAq[cur][h][s];          // elems s..s+3, one b128
                union { uint4 q4; short8 v; } af, b0, b1;
                af.q4 = aq;
                b0.q4 = bfr[0][ks]; b1.q4 = bfr[1][ks];
                acc0 = __builtin_amdgcn_mfma_f32_16x16x32_bf16(af.v, b0.v, acc0, 0, 0, 0);
                acc1 = __builtin_amdgcn_mfma_f32_16x16x32_bf16(af.v, b1.v, acc1, 0, 0, 0);
            }

            // fold: lane m holds dx0+m (acc0), dx0+16+m (acc1); x = c - dx.
            if (ci < 223) {
                const int xb = q + 31;
                #pragma unroll
                for (int r = 0; r < 4; ++r) {
                    int row = w * 16 + kg * 4 + r;
                    outT[row * XP + xb - m]      += acc0[r];
                    outT[row * XP + xb - 16 - m] += acc1[r];
                }
            }
        }
        __syncthreads();
    }

    // flush: outT -> flipped out (global atomics)
    const int xg0 = ci0 - 31;
    for (int e = tid; e < 64 * XT; e += 256) {
        int row = e / XT, xt = e - row * XT;
        int x = xg0 + xt;
        if (x >= 0 && x < N) {
            int y = yoff + row;
            atomicAdd(&out[(191 - y) * N + (191 - x)], outT[row * XP + xt]);
        }
    }
}

__global__ __launch_bounds__(256, 3) void s1_kernel(const uint32_t* __restrict__ Abf,
                                                    const uint32_t* __restrict__ Wt,
                                                    float* __restrict__ out) {
    s1_body(Abf, Wt, out, blockIdx.y * 64);
}

// PROBE: 8x s1 work; rep r accumulates into its own scratch plane (zeroed by
// prep_probe every call -> no cross-replay drift, same atomic contention).
__global__ __launch_bounds__(256, 3) void s1_probe(const uint32_t* __restrict__ Abf,
                                                   const uint32_t* __restrict__ Wt,
                                                   float* __restrict__ Pscr) {
    int rep = blockIdx.y / 3;
    s1_body(Abf, Wt, Pscr + rep * (N * N), (blockIdx.y % 3) * 64);
}

extern "C" void kernel_launch(void* const* d_in, const int* in_sizes, int n_in,
                              void* d_out, int out_size, void* d_ws, size_t ws_size,
                              hipStream_t stream) {
    const float* fr = (const float*)d_in[0];
    const float* fi = (const float*)d_in[1];
    const float* zp = (const float*)d_in[2];

    uint32_t* Abf  = (uint32_t*)d_ws;                  // 147456 u32
    uint32_t* Wt   = Abf + 384 * 384;                  // 36864 u32
    uint32_t* Abf2 = Wt + N * N;                       // probe scratch
    uint32_t* Wt2  = Abf2 + 384 * 384;
    float*    Pscr = (float*)(Wt2 + N * N);            // 8 * 36864 f32
    // total ws ~2.6 MB

    // real path (identical to round 10)
    prep_kernel<<<576, 256, 0, stream>>>(fr, fi, zp, Abf, Wt, (float*)d_out);
    s1_kernel<<<dim3(6 * NCHUNK, 3), 256, 0, stream>>>(Abf, Wt, (float*)d_out);
    // attribution probes (scratch only; deliberately inflate dur this round)
    prep_probe<<<576 * NREP_PREP, 256, 0, stream>>>(fr, fi, zp, Abf2, Wt2, Pscr);
    s1_probe<<<dim3(6 * NCHUNK, 3 * NREP_S1), 256, 0, stream>>>(Abf, Wt, Pscr);
}

// Round 12
// 35.443 us; speedup vs baseline: 3.2636x; 3.2636x over previous
//
#include <hip/hip_runtime.h>

#define N 192
#define CCHUNK 4              // c columns per s1 block (B-frag reuse)
#define NCHUNK 56             // 224 / 4 chunks of c per db
#define XT 35                 // x-tile width per block (32 + CCHUNK - 1)
#define XP 37                 // x-tile LDS pitch (f32) - conflict spreading

typedef __attribute__((ext_vector_type(8))) short short8;   // 8 bf16
typedef __attribute__((ext_vector_type(4))) float f32x4;

static __device__ __forceinline__ unsigned short f2bf(float x) {
    uint32_t u = __builtin_bit_cast(uint32_t, x);
    u += 0x7FFFu + ((u >> 16) & 1u);          // RNE (inputs finite)
    return (unsigned short)(u >> 16);
}

// ---------------------------------------------------------------------------
// prep: Abf[r][c] 384x384 packed (bf16 Ar, bf16 -Ai), zero pad row/col 383;
// Wt[dx][dy] packed (bf16 Wr, bf16 Wi); zero d_out (atomic target).
// amp = cos(atan2(rho,z))/R = z/(r2+z^2); ph = (2pi/0.5)*R.
// ---------------------------------------------------------------------------
__global__ __launch_bounds__(256) void prep_kernel(const float* __restrict__ fr,
                                                   const float* __restrict__ fi,
                                                   const float* __restrict__ zp,
                                                   uint32_t* __restrict__ Abf,
                                                   uint32_t* __restrict__ Wt,
                                                   float* __restrict__ out) {
    int idx = blockIdx.x * 256 + threadIdx.x;
    float z = zp[0];
    if (idx < 384 * 384) {
        int r = idx / 384, c = idx - r * 384;
        uint32_t pack = 0u;
        if (r < 383 && c < 383) {
            const float X0 = 191.00005f;      // 0.5*(2*192 + 1e-4) - 1
            float xr = (float)r - X0;
            float yc = (float)c - X0;
            float r2 = xr * xr + yc * yc;
            float R2 = r2 + z * z;
            float R  = sqrtf(R2);
            float amp = z / R2;
            float ph = 12.566371f * R;        // 2*pi/0.5
            float sv, cv;
            sincosf(ph, &sv, &cv);
            pack = (uint32_t)f2bf(amp * cv) | ((uint32_t)f2bf(-amp * sv) << 16);
        }
        Abf[idx] = pack;
    }
    if (idx < N * N) {
        int dy = idx / N, dx = idx - dy * N;
        Wt[dx * N + dy] = (uint32_t)f2bf(fr[idx]) | ((uint32_t)f2bf(fi[idx]) << 16);
        out[idx] = 0.f;                       // zero the atomic target each call
    }
}

// ---------------------------------------------------------------------------
// stage 1: G[c][y][dx] = sum_dy Ar[y+dy][c]*Wr[dy][dx] - Ai[..]*Wi[..] via
// mfma_f32_16x16x32_bf16 (K=384); dx-contraction folded in-block into LDS
// f32 tile outT[64][35] (x = c - dx), flushed with atomicAdd into flipped
// d_out. A columns staged as 16B quads, two per buffer (1 barrier / 2 c).
// B-frags loaded once and PINNED in VGPRs via asm (round-11 probe showed the
// compiler demoted them: VGPR_Count=64 < the 96 bfr needs -> inner loop was
// re-loading B from memory -> latency-bound at 23% MfmaUtil).
// Block = (db, chunk of 4 c's, y-third of 64 rows), 4 waves = 4 y-tiles.
// ---------------------------------------------------------------------------
__global__ __launch_bounds__(256, 2) void s1_kernel(const uint32_t* __restrict__ Abf,
                                                    const uint32_t* __restrict__ Wt,
                                                    float* __restrict__ out) {
    __shared__ uint4 colAq[2][2][384];        // [buf][col-of-pair][slot] 24.6 KB
    __shared__ float outT[64 * XP];           // 9.5 KB per-block output tile

    const int tid  = threadIdx.x;
    const int l    = tid & 63;
    const int w    = tid >> 6;                // wave -> y-tile within third
    const int db   = blockIdx.x / NCHUNK;
    const int ck   = blockIdx.x - db * NCHUNK;
    const int ci0  = ck * CCHUNK;
    const int dx0  = db * 32;
    const int yoff = blockIdx.y * 64;
    const int m    = l & 15;
    const int kg   = l >> 4;

    // B fragments: loaded once, pinned in registers for all 4 c's.
    uint4 bfr[2][12];
    #pragma unroll
    for (int t = 0; t < 2; ++t) {
        int dx = dx0 + t * 16 + m;
        #pragma unroll
        for (int ks = 0; ks < 12; ++ks) {
            bfr[t][ks] = *(const uint4*)(Wt + dx * N + ks * 16 + kg * 4);
            // pin: value becomes asm-opaque -> no rematerialization/demotion
            asm volatile("" : "+v"(bfr[t][ks].x), "+v"(bfr[t][ks].y),
                              "+v"(bfr[t][ks].z), "+v"(bfr[t][ks].w));
        }
    }

    // zero the output tile
    for (int e = tid; e < 64 * XP; e += 256) outT[e] = 0.f;

    // stage first column pair (rows c0, c0+1 of Abf; A symmetric: row c==col c)
    {
        const uint32_t* a0 = Abf + (dx0 + ci0) * 384;
        const uint32_t* a1 = Abf + (dx0 + ci0 + 1) * 384;
        for (int i = tid; i < 384; i += 256) {
            uint4 v0, v1;
            __builtin_memcpy(&v0, a0 + i, 16);
            __builtin_memcpy(&v1, a1 + i, 16);
            colAq[0][0][i] = v0;
            colAq[0][1][i] = v1;
        }
    }
    __syncthreads();

    for (int p = 0; p < CCHUNK; p += 2) {
        const int cur = (p >> 1) & 1;
        // prefetch next column pair into the other buffer
        if (p < CCHUNK - 2) {
            const uint32_t* a0 = Abf + (dx0 + ci0 + p + 2) * 384;
            const uint32_t* a1 = Abf + (dx0 + ci0 + p + 3) * 384;
            for (int i = tid; i < 384; i += 256) {
                uint4 v0, v1;
                __builtin_memcpy(&v0, a0 + i, 16);
                __builtin_memcpy(&v1, a1 + i, 16);
                colAq[cur ^ 1][0][i] = v0;
                colAq[cur ^ 1][1][i] = v1;
            }
        }

        #pragma unroll
        for (int h = 0; h < 2; ++h) {
            const int q  = p + h;
            const int ci = ci0 + q;
            f32x4 acc0 = {0.f, 0.f, 0.f, 0.f};
            f32x4 acc1 = {0.f, 0.f, 0.f, 0.f};
            const int srow = yoff + w * 16 + m;
            #pragma unroll
            for (int ks = 0; ks < 12; ++ks) {
                int s = srow + ks * 16 + kg * 4;      // <= 379
                uint4 aq = colAq[cur][h][s];          // elems s..s+3, one b128
                union { uint4 q4; short8 v; } af, b0, b1;
                af.q4 = aq;
                b0.q4 = bfr[0][ks]; b1.q4 = bfr[1][ks];
                acc0 = __builtin_amdgcn_mfma_f32_16x16x32_bf16(af.v, b0.v, acc0, 0, 0, 0);
                acc1 = __builtin_amdgcn_mfma_f32_16x16x32_bf16(af.v, b1.v, acc1, 0, 0, 0);
            }

            // fold: lane m holds dx0+m (acc0), dx0+16+m (acc1); x = c - dx
            // -> xt = (q+31) - m (acc0), (q+15) - m (acc1), all in [0, 35).
            // Rows disjoint per (w, kg) -> no races.
            if (ci < 223) {
                const int xb = q + 31;
                #pragma unroll
                for (int r = 0; r < 4; ++r) {
                    int row = w * 16 + kg * 4 + r;
                    outT[row * XP + xb - m]      += acc0[r];
                    outT[row * XP + xb - 16 - m] += acc1[r];
                }
            }
        }
        __syncthreads();   // colAq[cur^1] staged this iter is read next iter
    }

    // flush: outT -> flipped d_out (global atomics)
    const int xg0 = ci0 - 31;
    for (int e = tid; e < 64 * XT; e += 256) {
        int row = e / XT, xt = e - row * XT;
        int x = xg0 + xt;
        if (x >= 0 && x < N) {
            int y = yoff + row;
            atomicAdd(&out[(191 - y) * N + (191 - x)], outT[row * XP + xt]);
        }
    }
}

extern "C" void kernel_launch(void* const* d_in, const int* in_sizes, int n_in,
                              void* d_out, int out_size, void* d_ws, size_t ws_size,
                              hipStream_t stream) {
    const float* fr = (const float*)d_in[0];
    const float* fi = (const float*)d_in[1];
    const float* zp = (const float*)d_in[2];

    uint32_t* Abf = (uint32_t*)d_ws;                   // 384*384 u32 = 576 KB
    uint32_t* Wt  = Abf + 384 * 384;                   // 192*192 u32 = 144 KB

    prep_kernel<<<576, 256, 0, stream>>>(fr, fi, zp, Abf, Wt, (float*)d_out);
    s1_kernel<<<dim3(6 * NCHUNK, 3), 256, 0, stream>>>(Abf, Wt, (float*)d_out);
}

// Round 14
// 29.251 us; speedup vs baseline: 3.9545x; 1.2117x over previous
//
#include <hip/hip_runtime.h>

#define N 192
#define CCHUNK 8              // c columns per s1 block (B-frag reuse)
#define NCHUNK 28             // 224 / 8 chunks of c per db
#define XT 39                 // x-tile width per block (32 + CCHUNK - 1)
#define XP 41                 // x-tile LDS pitch (f32) - conflict spreading

typedef __attribute__((ext_vector_type(8))) short short8;   // 8 bf16
typedef __attribute__((ext_vector_type(4))) float f32x4;

static __device__ __forceinline__ unsigned short f2bf(float x) {
    uint32_t u = __builtin_bit_cast(uint32_t, x);
    u += 0x7FFFu + ((u >> 16) & 1u);          // RNE (inputs finite)
    return (unsigned short)(u >> 16);
}

// ---------------------------------------------------------------------------
// prep: Abf[r][c] 384x384 packed (bf16 Ar, bf16 -Ai), zero pad row/col 383;
// Wt[dx][dy] packed (bf16 Wr, bf16 Wi); zero d_out (atomic target).
// amp = cos(atan2(rho,z))/R = z/(r2+z^2); ph = (2pi/0.5)*R.
// ---------------------------------------------------------------------------
__global__ __launch_bounds__(256) void prep_kernel(const float* __restrict__ fr,
                                                   const float* __restrict__ fi,
                                                   const float* __restrict__ zp,
                                                   uint32_t* __restrict__ Abf,
                                                   uint32_t* __restrict__ Wt,
                                                   float* __restrict__ out) {
    int idx = blockIdx.x * 256 + threadIdx.x;
    float z = zp[0];
    if (idx < 384 * 384) {
        int r = idx / 384, c = idx - r * 384;
        uint32_t pack = 0u;
        if (r < 383 && c < 383) {
            const float X0 = 191.00005f;      // 0.5*(2*192 + 1e-4) - 1
            float xr = (float)r - X0;
            float yc = (float)c - X0;
            float r2 = xr * xr + yc * yc;
            float R2 = r2 + z * z;
            float R  = sqrtf(R2);
            float amp = z / R2;
            float ph = 12.566371f * R;        // 2*pi/0.5
            float sv, cv;
            sincosf(ph, &sv, &cv);
            pack = (uint32_t)f2bf(amp * cv) | ((uint32_t)f2bf(-amp * sv) << 16);
        }
        Abf[idx] = pack;
    }
    if (idx < N * N) {
        int dy = idx / N, dx = idx - dy * N;
        Wt[dx * N + dy] = (uint32_t)f2bf(fr[idx]) | ((uint32_t)f2bf(fi[idx]) << 16);
        out[idx] = 0.f;                       // zero the atomic target each call
    }
}

// ---------------------------------------------------------------------------
// stage 1 (ROUND-10 STRUCTURE, verified at 27.3 us + ONE change: asm pin on
// the B-fragments. Round-11 probe showed VGPR_Count=64 < the 96 regs bfr
// needs -> compiler demoted B and re-loaded it inside every K-loop).
//   G[c][y][dx] = sum_dy Ar[y+dy][c]*Wr[dy][dx] - Ai[..]*Wi[..]
// via mfma_f32_16x16x32_bf16 (K=384); dx-contraction folded in-block into
// LDS f32 tile outT[64][39] (x = c - dx), flushed with atomicAdd into
// flipped d_out. A columns staged as 16B quads, two per buffer (1 barrier
// per 2 c's). Block = (db, chunk of 8 c's, y-third of 64 rows), 4 waves.
// ---------------------------------------------------------------------------
__global__ __launch_bounds__(256, 3) void s1_kernel(const uint32_t* __restrict__ Abf,
                                                    const uint32_t* __restrict__ Wt,
                                                    float* __restrict__ out) {
    __shared__ uint4 colAq[2][2][384];        // [buf][col-of-pair][slot] 24.6 KB
    __shared__ float outT[64 * XP];           // 10.5 KB per-block output tile

    const int tid  = threadIdx.x;
    const int l    = tid & 63;
    const int w    = tid >> 6;                // wave -> y-tile within third
    const int db   = blockIdx.x / NCHUNK;
    const int ck   = blockIdx.x - db * NCHUNK;
    const int ci0  = ck * CCHUNK;
    const int dx0  = db * 32;
    const int yoff = blockIdx.y * 64;
    const int m    = l & 15;
    const int kg   = l >> 4;

    // B fragments: loaded once, PINNED in registers for all 8 c's.
    uint4 bfr[2][12];
    #pragma unroll
    for (int t = 0; t < 2; ++t) {
        int dx = dx0 + t * 16 + m;
        #pragma unroll
        for (int ks = 0; ks < 12; ++ks) {
            bfr[t][ks] = *(const uint4*)(Wt + dx * N + ks * 16 + kg * 4);
            // pin: value becomes asm-opaque -> no rematerialization/demotion
            asm volatile("" : "+v"(bfr[t][ks].x), "+v"(bfr[t][ks].y),
                              "+v"(bfr[t][ks].z), "+v"(bfr[t][ks].w));
        }
    }

    // zero the output tile
    for (int e = tid; e < 64 * XP; e += 256) outT[e] = 0.f;

    // stage first column pair (rows c0, c0+1 of Abf; A symmetric: row c==col c)
    {
        const uint32_t* a0 = Abf + (dx0 + ci0) * 384;
        const uint32_t* a1 = Abf + (dx0 + ci0 + 1) * 384;
        for (int i = tid; i < 384; i += 256) {
            uint4 v0, v1;
            __builtin_memcpy(&v0, a0 + i, 16);
            __builtin_memcpy(&v1, a1 + i, 16);
            colAq[0][0][i] = v0;
            colAq[0][1][i] = v1;
        }
    }
    __syncthreads();

    for (int p = 0; p < CCHUNK; p += 2) {
        const int cur = (p >> 1) & 1;
        // prefetch next column pair into the other buffer
        if (p < CCHUNK - 2) {
            const uint32_t* a0 = Abf + (dx0 + ci0 + p + 2) * 384;
            const uint32_t* a1 = Abf + (dx0 + ci0 + p + 3) * 384;
            for (int i = tid; i < 384; i += 256) {
                uint4 v0, v1;
                __builtin_memcpy(&v0, a0 + i, 16);
                __builtin_memcpy(&v1, a1 + i, 16);
                colAq[cur ^ 1][0][i] = v0;
                colAq[cur ^ 1][1][i] = v1;
            }
        }

        #pragma unroll
        for (int h = 0; h < 2; ++h) {
            const int q  = p + h;
            const int ci = ci0 + q;
            f32x4 acc0 = {0.f, 0.f, 0.f, 0.f};
            f32x4 acc1 = {0.f, 0.f, 0.f, 0.f};
            const int srow = yoff + w * 16 + m;
            #pragma unroll
            for (int ks = 0; ks < 12; ++ks) {
                int s = srow + ks * 16 + kg * 4;      // <= 379
                uint4 aq = colAq[cur][h][s];          // elems s..s+3, one b128
                union { uint4 q4; short8 v; } af, b0, b1;
                af.q4 = aq;
                b0.q4 = bfr[0][ks]; b1.q4 = bfr[1][ks];
                acc0 = __builtin_amdgcn_mfma_f32_16x16x32_bf16(af.v, b0.v, acc0, 0, 0, 0);
                acc1 = __builtin_amdgcn_mfma_f32_16x16x32_bf16(af.v, b1.v, acc1, 0, 0, 0);
            }

            // fold: lane m holds dx0+m (acc0), dx0+16+m (acc1); x = c - dx
            // -> xt = (q+31) - m (acc0), (q+15) - m (acc1), all in [0, 39).
            // Rows disjoint per (w, kg) -> no races.
            if (ci < 223) {
                const int xb = q + 31;
                #pragma unroll
                for (int r = 0; r < 4; ++r) {
                    int row = w * 16 + kg * 4 + r;
                    outT[row * XP + xb - m]      += acc0[r];
                    outT[row * XP + xb - 16 - m] += acc1[r];
                }
            }
        }
        __syncthreads();   // colAq[cur^1] staged this iter is read next iter
    }

    // flush: outT -> flipped d_out (global atomics)
    const int xg0 = ci0 - 31;
    for (int e = tid; e < 64 * XT; e += 256) {
        int row = e / XT, xt = e - row * XT;
        int x = xg0 + xt;
        if (x >= 0 && x < N) {
            int y = yoff + row;
            atomicAdd(&out[(191 - y) * N + (191 - x)], outT[row * XP + xt]);
        }
    }
}

extern "C" void kernel_launch(void* const* d_in, const int* in_sizes, int n_in,
                              void* d_out, int out_size, void* d_ws, size_t ws_size,
                              hipStream_t stream) {
    const float* fr = (const float*)d_in[0];
    const float* fi = (const float*)d_in[1];
    const float* zp = (const float*)d_in[2];

    uint32_t* Abf = (uint32_t*)d_ws;                   // 384*384 u32 = 576 KB
    uint32_t* Wt  = Abf + 384 * 384;                   // 192*192 u32 = 144 KB

    prep_kernel<<<576, 256, 0, stream>>>(fr, fi, zp, Abf, Wt, (float*)d_out);
    s1_kernel<<<dim3(6 * NCHUNK, 3), 256, 0, stream>>>(Abf, Wt, (float*)d_out);
}